// Round 12
// baseline (221.926 us; speedup 1.0000x reference)
//
#include <hip/hip_runtime.h>

// ---------------------------------------------------------------------------
// MoE top-2 sparse. MI355X (gfx950). B=2,L=1024,D=768,E=16,F=3072,K=2
// GEMM: T3/T4-style counted-vmcnt pipeline. 128x128 tile, BK=64, 512 thr
// (8 waves 2Mx4N, wave tile 64x32). TRIPLE-buffered LDS (A bf16 16KB +
// B fp32 32KB = 48KB/buf, 144KB total): stage(t+2) via global_load_lds for
// BOTH operands while compute(t) runs; end-of-step sync is raw s_barrier +
// s_waitcnt vmcnt(6) -- loads stay in flight ACROSS barriers (never drain 0).
// B kept fp32 in LDS; fp32->bf16 conversion on the READ side (cvt_pk x4 per
// frag) -- removes the per-step auto-vmcnt drain reg-staging caused (R4-R11:
// ~1.5KB/CU in flight / 600cyc = the 3.4 TB/s pull wall).
// Swizzles: A slot^(row&7) (R4-verified 0-conflict); B slot^(row&15), same
// both-sides construction via pre-swizzled gll sources. XCD pin bid%16==e.
// fc2: K=3072 as 4x768 k-splits -> bf16 partial planes (R5-verified).
// ---------------------------------------------------------------------------

#define D_      768
#define E_      16
#define F_      3072
#define NTOK    2048
#define NROWS   4096
#define SEG     384
#define MAXROWS 6144
#define BK      64
#define NT      12           // 768 / BK per block

typedef __attribute__((ext_vector_type(4))) unsigned int   u32x4;
typedef __attribute__((ext_vector_type(8))) unsigned short u16x8;
typedef __attribute__((ext_vector_type(8))) short          v8bf;
typedef __attribute__((ext_vector_type(4))) float          f32x4;

static __device__ inline unsigned short f2bf(float f) {
    unsigned u = __builtin_bit_cast(unsigned, f);
    u += 0x7fffu + ((u >> 16) & 1u);      // RNE
    return (unsigned short)(u >> 16);
}
static __device__ __forceinline__ unsigned cvt_pk_bf16(float lo, float hi) {
    unsigned r;
    asm("v_cvt_pk_bf16_f32 %0, %1, %2" : "=v"(r) : "v"(lo), "v"(hi));
    return r;
}
static __device__ __forceinline__ void gll16(const void* g, void* l) {
    __builtin_amdgcn_global_load_lds(
        (const __attribute__((address_space(1))) unsigned int*)g,
        (__attribute__((address_space(3))) unsigned int*)l, 16, 0, 0);
}

// ---------------------------------------------------------------------------
// 1. Router: softmax over 16, top-2 (ties -> lowest idx), gates = raw probs
// ---------------------------------------------------------------------------
__global__ void router_kernel(const float* __restrict__ x, const float* __restrict__ wr,
                              int* __restrict__ idx, float* __restrict__ gate) {
    const int tok  = blockIdx.x;
    const int lane = threadIdx.x;          // 64
    const float* xr = x + (size_t)tok * D_;

    float xv[12];
#pragma unroll
    for (int j = 0; j < 12; ++j) xv[j] = xr[lane + 64 * j];

    float lg[E_];
#pragma unroll
    for (int e = 0; e < E_; ++e) {
        const float* w = wr + (size_t)e * D_;
        float acc = 0.f;
#pragma unroll
        for (int j = 0; j < 12; ++j) acc += xv[j] * w[lane + 64 * j];
#pragma unroll
        for (int s = 32; s > 0; s >>= 1) acc += __shfl_xor(acc, s, 64);
        lg[e] = acc;
    }

    float m = lg[0];
#pragma unroll
    for (int e = 1; e < E_; ++e) m = fmaxf(m, lg[e]);
    float p[E_], s = 0.f;
#pragma unroll
    for (int e = 0; e < E_; ++e) { p[e] = expf(lg[e] - m); s += p[e]; }
    const float inv = 1.f / s;

    int e0 = 0; float p0 = p[0];
#pragma unroll
    for (int e = 1; e < E_; ++e) if (p[e] > p0) { p0 = p[e]; e0 = e; }
    int e1 = -1; float p1 = -1.f;
#pragma unroll
    for (int e = 0; e < E_; ++e) if (e != e0 && p[e] > p1) { p1 = p[e]; e1 = e; }

    if (lane == 0) {
        idx[tok * 2 + 0] = e0;  gate[tok * 2 + 0] = p0 * inv;
        idx[tok * 2 + 1] = e1;  gate[tok * 2 + 1] = p1 * inv;
    }
}

// ---------------------------------------------------------------------------
// 2. Build: fixed SEG-sized segments per expert; meta[e] = clamped count
// ---------------------------------------------------------------------------
__global__ void build_kernel(const int* __restrict__ idx, const float* __restrict__ gate,
                             int* __restrict__ rowmap, float* __restrict__ rowgate,
                             int* __restrict__ posOf, int* __restrict__ meta) {
    __shared__ int cur[E_];
    const int t = threadIdx.x;             // 256
    if (t < E_) cur[t] = 0;
    __syncthreads();
    for (int i = t; i < MAXROWS; i += 256) { rowmap[i] = 0; rowgate[i] = 0.f; }
    __syncthreads();
    for (int i = t; i < NROWS; i += 256) {
        const int e = idx[i];
        const int o = atomicAdd(&cur[e], 1);
        if (o < SEG) {
            const int pos = e * SEG + o;
            rowmap[pos]  = i >> 1;
            rowgate[pos] = gate[i];
            posOf[i]     = pos;
        } else {
            posOf[i] = e * SEG;            // ~8-sigma overflow; degrade gracefully
        }
    }
    __syncthreads();
    if (t < E_) meta[t] = cur[t] < SEG ? cur[t] : SEG;
}

// ---------------------------------------------------------------------------
// 3. Gather x rows into bf16 Xg
// ---------------------------------------------------------------------------
__global__ void gather_kernel(const float* __restrict__ x, const int* __restrict__ rowmap,
                              unsigned short* __restrict__ Xg) {
    const int g = blockIdx.x * 256 + threadIdx.x;
    const int pos = g / (D_ / 8), c = g % (D_ / 8);
    const int tok = rowmap[pos];
    const float* src = x + (size_t)tok * D_ + c * 8;
    f32x4 a = *(const f32x4*)src;
    f32x4 b = *(const f32x4*)(src + 4);
    u16x8 o;
    o[0] = f2bf(a[0]); o[1] = f2bf(a[1]); o[2] = f2bf(a[2]); o[3] = f2bf(a[3]);
    o[4] = f2bf(b[0]); o[5] = f2bf(b[1]); o[6] = f2bf(b[2]); o[7] = f2bf(b[3]);
    *(u16x8*)(Xg + (size_t)pos * D_ + c * 8) = o;
}

// ---------------------------------------------------------------------------
// 4/5. Counted-vmcnt pipelined GEMM (see file header).
//   Decode: bid = e + 16*(nt + NTl*(mtl + 3*split)) -> bid%16 = e (XCD pin).
//   A LDS: row = 128B (8 slots), phys slot = logical ^ (row&7).
//   B LDS: fp32 row = 256B (16 slots), phys slot = logical ^ (row&15).
//   Both staged by global_load_lds with pre-swizzled per-lane sources (T21).
//   EPI=0: +bias, exact gelu -> bf16 H.  EPI=1: (+bias if split0)*gate ->
//   bf16 plane (split0 -> C0, split s>0 -> C123 + (s-1)*MAXROWS*N).
// ---------------------------------------------------------------------------
template <int EPI>
__global__ __launch_bounds__(512, 2)
void gemm_kernel(const unsigned short* __restrict__ Ag, const float* __restrict__ Bw,
                 const float* __restrict__ bias, unsigned short* __restrict__ C0,
                 unsigned short* __restrict__ C123, const float* __restrict__ rowgate,
                 const int* __restrict__ meta, const int K, const int N, const int NTl) {
    const int bid   = blockIdx.x;
    const int e     = bid & 15;
    const int rest  = bid >> 4;
    const int nt    = rest % NTl;
    const int rest2 = rest / NTl;
    const int mtl   = rest2 % 3;
    const int split = rest2 / 3;

    const int cnt = meta[e];
    if (mtl * 128 >= cnt) return;          // fully-pad block (before any barrier)
    const int m0   = e * SEG + mtl * 128;
    const int n0   = nt * 128;
    const int kOff = split * 768;

    __shared__ alignas(16) unsigned short As[3][128 * 64];   // 3 x 16 KB bf16
    __shared__ alignas(16) float           Bsf[3][128 * 64];  // 3 x 32 KB fp32

    const int t    = threadIdx.x;          // 512
    const int lane = t & 63;
    const int wv   = t >> 6;               // 0..7
    const int wm   = wv >> 2;              // 0..1 : 64-row half
    const int wn   = wv & 3;               // 0..3 : 32-col slice
    const int r16  = lane & 15;
    const int h    = lane >> 4;            // 0..3

    const bool act = (mtl * 128 + wm * 64) < cnt;   // wave-band pad skip

    f32x4 acc[4][2];
#pragma unroll
    for (int i = 0; i < 4; ++i) { acc[i][0] = (f32x4){0,0,0,0}; acc[i][1] = (f32x4){0,0,0,0}; }

    // ---- A gll source (verified R4 pattern): call j covers rows wv*16+j*8+(L>>3);
    //      linear dest slot (L&7) holds logical slot (L&7)^((L>>3)&7).
    const unsigned short* srcA =
        Ag + (size_t)(m0 + wv * 16 + (lane >> 3)) * K + kOff
           + (((lane & 7) ^ ((lane >> 3) & 7)) << 3);

    // ---- B gll sources: call j covers rows wv*16+j*4+(L>>4); dest slot (L&15)
    //      holds logical slot (L&15)^((row)&15), row&15 = (L>>4)+j*4.
    const float* srcB[4];
#pragma unroll
    for (int j = 0; j < 4; ++j) {
        const int row = wv * 16 + j * 4 + (lane >> 4);
        const int ss  = (lane & 15) ^ ((lane >> 4) + j * 4);
        srcB[j] = Bw + ((size_t)e * N + n0 + row) * K + kOff + ss * 4;
    }

    auto stage = [&](int buf, int kt) {
#pragma unroll
        for (int j = 0; j < 2; ++j)   // A: 2 calls x 1KB
            gll16(srcA + (size_t)(j * 8) * K + kt * BK,
                  &As[buf][(wv * 16 + j * 8) * 64]);
#pragma unroll
        for (int j = 0; j < 4; ++j)   // B: 4 calls x 1KB (fp32, raw copy)
            gll16(srcB[j] + kt * BK,
                  &Bsf[buf][(wv * 16 + j * 4) * 64]);
    };
    auto compute = [&](int buf) {
#pragma unroll
        for (int ks = 0; ks < 2; ++ks) {
            v8bf bfr[2];
#pragma unroll
            for (int nf = 0; nf < 2; ++nf) {
                const int row = wn * 32 + nf * 16 + r16;   // row&15 == r16
                const int s0  = ks * 8 + h * 2;
                const f32x4 lo = *(const f32x4*)&Bsf[buf][row * 64 + ((s0 ^ r16) << 2)];
                const f32x4 hi = *(const f32x4*)&Bsf[buf][row * 64 + (((s0 + 1) ^ r16) << 2)];
                u32x4 q;
                q[0] = cvt_pk_bf16(lo[0], lo[1]);
                q[1] = cvt_pk_bf16(lo[2], lo[3]);
                q[2] = cvt_pk_bf16(hi[0], hi[1]);
                q[3] = cvt_pk_bf16(hi[2], hi[3]);
                bfr[nf] = __builtin_bit_cast(v8bf, q);
            }
#pragma unroll
            for (int mf = 0; mf < 4; ++mf) {
                const int rowA = wm * 64 + mf * 16 + r16;  // rowA&7 == r16&7
                const v8bf af = *(const v8bf*)
                    &As[buf][rowA * 64 + (((ks * 4 + h) ^ (r16 & 7)) << 3)];
#pragma unroll
                for (int nf = 0; nf < 2; ++nf)
                    acc[mf][nf] = __builtin_amdgcn_mfma_f32_16x16x32_bf16(
                        af, bfr[nf], acc[mf][nf], 0, 0, 0);
            }
        }
    };

    // ---- prologue: two stages in flight, wait for the first only ----
    stage(0, 0);
    stage(1, 1);
    asm volatile("s_waitcnt vmcnt(6)" ::: "memory");
    __builtin_amdgcn_s_barrier();
    __builtin_amdgcn_sched_barrier(0);

    // ---- main loop: counted vmcnt, never 0 until the tail ----
#pragma unroll
    for (int kt = 0; kt < NT; ++kt) {
        if (kt + 2 < NT) stage((kt + 2) % 3, kt + 2);
        if (act) compute(kt % 3);
        if (kt + 1 < NT) {
            if (kt + 2 < NT) { asm volatile("s_waitcnt vmcnt(6)" ::: "memory"); }
            else             { asm volatile("s_waitcnt vmcnt(0)" ::: "memory"); }
            __builtin_amdgcn_s_barrier();
            __builtin_amdgcn_sched_barrier(0);
        }
    }

    // ---- epilogue: C/D layout col = lane&15, row = (lane>>4)*4 + reg ----
    if (!act) return;
    unsigned short* myC = (EPI == 0 || split == 0)
                        ? C0 : C123 + (size_t)(split - 1) * MAXROWS * N;
#pragma unroll
    for (int mf = 0; mf < 4; ++mf) {
#pragma unroll
        for (int jj = 0; jj < 4; ++jj) {
            const int rr = m0 + wm * 64 + mf * 16 + h * 4 + jj;
            float gt = 0.f;
            if (EPI == 1) gt = rowgate[rr];
#pragma unroll
            for (int nf = 0; nf < 2; ++nf) {
                const int cc = n0 + wn * 32 + nf * 16 + r16;
                float v = acc[mf][nf][jj];
                if (EPI == 0) {
                    v += bias[e * N + cc];
                    const float ge = 0.5f * v * (1.f + erff(v * 0.70710678118654752f));
                    myC[(size_t)rr * N + cc] = f2bf(ge);
                } else {
                    if (split == 0) v += bias[e * N + cc];
                    myC[(size_t)rr * N + cc] = f2bf(v * gt);
                }
            }
        }
    }
}

// ---------------------------------------------------------------------------
// 6. Combine: out = x + sum_s (Yp_s[p0] + Yp_s[p1])  (bf16 planes)
// ---------------------------------------------------------------------------
__global__ void combine_kernel(const float* __restrict__ x,
                               const unsigned short* __restrict__ Yp0,
                               const unsigned short* __restrict__ Yp123,
                               const int* __restrict__ posOf, float* __restrict__ out,
                               const int nsplit) {
    const int tok = blockIdx.x;
    const int t   = threadIdx.x;           // 192 * 4 = 768
    const int p0 = posOf[tok * 2 + 0];
    const int p1 = posOf[tok * 2 + 1];
    f32x4 v = *(const f32x4*)(x + (size_t)tok * D_ + t * 4);
    for (int s = 0; s < nsplit; ++s) {
        const unsigned short* base = (s == 0) ? Yp0
                                   : Yp123 + (size_t)(s - 1) * MAXROWS * D_;
        const unsigned short* a = base + (size_t)p0 * D_ + t * 4;
        const unsigned short* b = base + (size_t)p1 * D_ + t * 4;
#pragma unroll
        for (int i = 0; i < 4; ++i) {
            v[i] += __builtin_bit_cast(float, (unsigned)a[i] << 16);
            v[i] += __builtin_bit_cast(float, (unsigned)b[i] << 16);
        }
    }
    *(f32x4*)(out + (size_t)tok * D_ + t * 4) = v;
}

// ---------------------------------------------------------------------------
extern "C" void kernel_launch(void* const* d_in, const int* in_sizes, int n_in,
                              void* d_out, int out_size, void* d_ws, size_t ws_size,
                              hipStream_t stream) {
    const float* x  = (const float*)d_in[0];
    const float* wr = (const float*)d_in[1];
    const float* w1 = (const float*)d_in[2];
    const float* b1 = (const float*)d_in[3];
    const float* w2 = (const float*)d_in[4];
    const float* b2 = (const float*)d_in[5];
    float* out = (float*)d_out;

    char* wsp = (char*)d_ws;
    int*            idxP    = (int*)(wsp + 0);
    float*          gateP   = (float*)(wsp + 16384);
    int*            posOf   = (int*)(wsp + 32768);
    int*            rowmap  = (int*)(wsp + 49152);
    float*          rowgate = (float*)(wsp + 73728);
    int*            meta    = (int*)(wsp + 98304);
    const size_t    XG_OFF  = 131072;
    const size_t    PLANE   = (size_t)MAXROWS * D_ * 2;        // 9.44 MB
    const size_t    H_OFF   = XG_OFF + PLANE;
    const size_t    H_B     = (size_t)MAXROWS * F_ * 2;        // 37.75 MB
    unsigned short* Xg    = (unsigned short*)(wsp + XG_OFF);
    unsigned short* H     = (unsigned short*)(wsp + H_OFF);
    unsigned short* Yp0   = Xg;                                // plane 0 overlays Xg
    unsigned short* Yp123 = (unsigned short*)(wsp + H_OFF + H_B);

    router_kernel<<<NTOK, 64, 0, stream>>>(x, wr, idxP, gateP);
    build_kernel<<<1, 256, 0, stream>>>(idxP, gateP, rowmap, rowgate, posOf, meta);
    gather_kernel<<<MAXROWS * (D_ / 8) / 256, 256, 0, stream>>>(x, rowmap, Xg);

    // fc1: K=768 (12 steps), N=3072, NTl=24, 3 m-tiles, no split -> grid 1152
    gemm_kernel<0><<<16 * 24 * 3, 512, 0, stream>>>(
        Xg, w1, b1, H, (unsigned short*)nullptr, rowgate, meta, D_, F_, 24);

    // fc2: K=3072 as 4x768 k-splits, NTl=6, 3 m-tiles -> grid 1152
    gemm_kernel<1><<<16 * 6 * 3 * 4, 512, 0, stream>>>(
        H, w2, b2, Yp0, Yp123, rowgate, meta, F_, D_, 6);
    combine_kernel<<<NTOK, 192, 0, stream>>>(x, Yp0, Yp123, posOf, out, 4);
}